// Round 10
// baseline (573.836 us; speedup 1.0000x reference)
//
#include <hip/hip_runtime.h>
#include <hip/hip_bf16.h>

// ---------------- problem constants ----------------
#define BB 8
#define SS 2000
#define IN_CH 120
#define NPTS 10000
#define IC 512
#define CATCH 248
#define CATPAD 256
#define MROWS 16000          // B*S
#define MROWS4 64000         // B*S*DIRS
#define NSLICE 16
#define PTS_PER_SLICE 625

typedef __bf16 bf16x8 __attribute__((ext_vector_type(8)));
typedef float f32x4 __attribute__((ext_vector_type(4)));

#define DEVI __device__ __forceinline__

DEVI unsigned short f2bf(float f) {
    __hip_bfloat16 h = __float2bfloat16(f);
    return __builtin_bit_cast(unsigned short, h);
}
DEVI float bf2f(unsigned short u) {
    unsigned int x = ((unsigned int)u) << 16;
    return __builtin_bit_cast(float, x);
}
DEVI float leaky(float x) { return x > 0.f ? x : 0.1f * x; }
DEVI unsigned int pk2(float a, float b) {
    return (unsigned int)f2bf(a) | ((unsigned int)f2bf(b) << 16);
}

DEVI void gload16(const void* g, void* l) {
    __builtin_amdgcn_global_load_lds(
        (const unsigned int __attribute__((address_space(1)))*)g,
        (unsigned int __attribute__((address_space(3)))*)l, 16, 0, 0);
}

// XCD-chunked bijective swizzle (m204)
DEVI int xcd_swizzle() {
    int nwg = (int)gridDim.x;
    int orig = (int)blockIdx.x;
    int q = nwg >> 3, r = nwg & 7;
    int xcd = orig & 7, pos = orig >> 3;
    int base = xcd < r ? xcd * (q + 1) : r * (q + 1) + (xcd - r) * q;
    return base + pos;
}

// packed u32 global store of a 4-row x 2-col micro-tile (R4/R5-verified pairing):
// lanes fr, fr^1 exchange; even lane writes rows mbase+0,1; odd writes mbase+2,3.
DEVI void pack_store_g(unsigned short* __restrict__ out, size_t mbase, int np, int fr,
                       float v0, float v1, float v2, float v3) {
    unsigned int p01 = pk2(v0, v1), p23 = pk2(v2, v3);
    unsigned int q01 = (unsigned int)__shfl_xor((int)p01, 1);
    unsigned int q23 = (unsigned int)__shfl_xor((int)p23, 1);
    if (!(fr & 1)) {
        *(unsigned int*)(out + (mbase + 0) * 512 + np) =
            (p01 & 0xffffu) | ((q01 & 0xffffu) << 16);
        *(unsigned int*)(out + (mbase + 1) * 512 + np) =
            (p01 >> 16) | (q01 & 0xffff0000u);
    } else {
        *(unsigned int*)(out + (mbase + 2) * 512 + np) =
            (q23 & 0xffffu) | ((p23 & 0xffffu) << 16);
        *(unsigned int*)(out + (mbase + 3) * 512 + np) =
            (q23 >> 16) | (p23 & 0xffff0000u);
    }
}

// ---------------- workspace layout (bytes) ----------------
static const size_t OFF_FEATS  = 0;            // 8*128 f32
static const size_t OFF_PROJWT = 4096;         // 512*256 bf16
static const size_t OFF_RES0WT = 266240;       // 512*256 bf16
static const size_t OFF_RES1WT = 528384;       // 512*512 bf16
static const size_t OFF_LAYWT  = 1052672;      // 6*512*512 bf16
static const size_t OFF_MYIN   = 4198400;      // 16000*256 bf16
static const size_t OFF_R0     = 12390400;     // 16000*512 bf16
static const size_t OFF_R      = 28774400;     // 16000*512 bf16
static const size_t OFF_A0     = 45158400;     // 64000*512 bf16
static const size_t OFF_A1     = 110694400;    // 64000*512 bf16
// feats partials overlap A0 (consumed before proj writes A0)

// ---------------- weight convert: f32 [L][K][N] -> bf16 [L][N][Kpad] ----
__global__ void wconv_k(const float* __restrict__ src, unsigned short* __restrict__ dst,
                        int K, int Kpad, int N, int total) {
    int idx = blockIdx.x * 256 + threadIdx.x;
    if (idx >= total) return;
    int k = idx % Kpad;
    int rem = idx / Kpad;
    int n = rem % N;
    int l = rem / N;
    float v = (k < K) ? src[((size_t)l * K + k) * N + n] : 0.f;
    dst[idx] = f2bf(v);
}

// ---------------- kernel regression stage 1 ----------------
__global__ __launch_bounds__(256) void feats_part_k(
    const float* __restrict__ gxy, const float* __restrict__ goff,
    const float* __restrict__ bws, const float* __restrict__ g0,
    const float* __restrict__ sloc, float* __restrict__ partial) {
    int bq = blockIdx.x;
    int b = bq >> 1, q = bq & 1;
    float qx = sloc[b * 4 + q * 2 + 0];
    float qy = sloc[b * 4 + q * 2 + 1];
    int i0 = blockIdx.y * PTS_PER_SLICE;
    int iend = i0 + PTS_PER_SLICE;
    float swt = 0.f;
    float sf[64];
#pragma unroll
    for (int c = 0; c < 64; c++) sf[c] = 0.f;
    for (int i = i0 + threadIdx.x; i < iend; i += 256) {
        float gx = gxy[i * 2 + 0] + tanhf(goff[i * 2 + 0]) * 0.1f;
        float gy = gxy[i * 2 + 1] + tanhf(goff[i * 2 + 1]) * 0.1f;
        float bw = fminf(fmaxf(bws[i], 0.1f), 0.5f);
        float dx = qx - gx, dy = qy - gy;
        float w = expf(-(dx * dx + dy * dy) / (bw * bw));
        swt += w;
#pragma unroll
        for (int c = 0; c < 64; c++) sf[c] += w * g0[(size_t)i * 64 + c];
    }
#pragma unroll
    for (int c = 0; c < 64; c++)
        for (int o = 32; o; o >>= 1) sf[c] += __shfl_down(sf[c], o);
    for (int o = 32; o; o >>= 1) swt += __shfl_down(swt, o);
    __shared__ float red[4][65];
    int lane = threadIdx.x & 63, wv = threadIdx.x >> 6;
    if (lane == 0) {
#pragma unroll
        for (int c = 0; c < 64; c++) red[wv][c] = sf[c];
        red[wv][64] = swt;
    }
    __syncthreads();
    size_t base = (size_t)(blockIdx.y * 16 + bq) * 72;
    if (threadIdx.x < 64) {
        int c = threadIdx.x;
        partial[base + c] = red[0][c] + red[1][c] + red[2][c] + red[3][c];
        if (c == 0)
            partial[base + 64] = red[0][64] + red[1][64] + red[2][64] + red[3][64];
    }
}

__global__ __launch_bounds__(128) void feats_reduce_k(
    const float* __restrict__ partial, float* __restrict__ feats) {
    int bq = blockIdx.x;
    __shared__ float s[66];
    int t = threadIdx.x;
    if (t < 65) {
        float acc = 0.f;
        for (int sl = 0; sl < NSLICE; ++sl)
            acc += partial[(size_t)(sl * 16 + bq) * 72 + t];
        s[t] = acc;
    }
    __syncthreads();
    if (t < 64) {
        int b = bq >> 1, q = bq & 1;
        feats[b * 128 + q * 64 + t] = s[t] / s[64];
    }
}

// ---------------- build my_input bf16 [16000][256] ----------------
__global__ void build_k(const float* __restrict__ feats, const float* __restrict__ inp,
                        unsigned short* __restrict__ dst) {
    int idx = blockIdx.x * 256 + threadIdx.x;
    int c = idx & 255;
    int m = idx >> 8;
    int b = m / SS;
    float v;
    if (c < 128) v = feats[b * 128 + c];
    else if (c < CATCH) v = inp[(size_t)m * IN_CH + (c - 128)];
    else v = 0.f;
    dst[idx] = f2bf(v);
}

// ---------------- MFMA GEMM: 128x128 tile, BK=64, asymmetric 3A/2B-buffer pipeline ----
// LDS per 16KB tile: [8 kchunk][128 row][8 k] bf16 (conflict-free b128, R6/R7-verified).
// A 3-buffered, B 2-buffered = 80KB dynamic -> 2 blocks/CU. Per step t: issue B(t+1)
// then A(t+2); end-of-compute waits vmcnt(4) (A(t+2) 4 loads stay in flight across
// the barrier). Cover: B ~1 phase (L2-hot weights), A ~2 phases (L3/HBM stream).
// EPI: 0=PROJ(expand x4 +ch0, leaky) 1=LAYER 2=LAYER+RES 3=LAYER_LAST
//      4=SIMPLE+leaky 5=SIMPLE
template <int EPI, int KK>
__global__ __launch_bounds__(256) void gemm_k(
    const unsigned short* __restrict__ A, const unsigned short* __restrict__ BT,
    unsigned short* __restrict__ out,
    const float* __restrict__ bias, const float* __restrict__ chan,
    const unsigned short* __restrict__ resid) {
    extern __shared__ __align__(16) unsigned short smem[];
    unsigned short* smemA = smem;                 // 3 * 8192 ushorts
    unsigned short* smemB = smem + 3 * 8192;      // 2 * 8192 ushorts
    const int tid = threadIdx.x;
    const int lane = tid & 63, wv = tid >> 6;
    const int wm = wv >> 1, wn = wv & 1;
    const int c8 = lane >> 4;                     // 0..3
    const int fr = lane & 15;

    const int swz = xcd_swizzle();
    const int bx = swz >> 2, by = swz & 3;

    // fragment LDS offsets (ushort units): [frag][half]; chunk = h*4+c8, stride 1024
    int aoff[4][2], boff[4][2];
#pragma unroll
    for (int i = 0; i < 4; i++) {
#pragma unroll
        for (int h = 0; h < 2; h++) {
            aoff[i][h] = (h * 4 + c8) * 1024 + (wm * 64 + i * 16 + fr) * 8;
            boff[i][h] = (h * 4 + c8) * 1024 + (wn * 64 + i * 16 + fr) * 8;
        }
    }
    // staging: 4 issues of 16B per thread per 16KB tile; linear LDS dest
    int ldso[4];
    size_t srcoff[4];
    const unsigned short* Ab = A + (size_t)bx * 128 * KK;
    const unsigned short* Bb = BT + (size_t)by * 128 * KK;
#pragma unroll
    for (int t = 0; t < 4; t++) {
        int o = t * 4096 + tid * 16;              // bytes, 0..16368
        int ck = o >> 11;                         // 0..7
        int r = (o >> 4) & 127;
        ldso[t] = o >> 1;                         // ushort units
        srcoff[t] = (size_t)r * KK + ck * 8;
    }

#define STAGE_A(kt, bf)                                                        \
    {                                                                          \
        const int ko = (kt) << 6;                                              \
        _Pragma("unroll") for (int t = 0; t < 4; t++)                          \
            gload16(Ab + srcoff[t] + ko, &smemA[(bf) * 8192 + ldso[t]]);       \
    }
#define STAGE_B(kt, bf)                                                        \
    {                                                                          \
        const int ko = (kt) << 6;                                              \
        _Pragma("unroll") for (int t = 0; t < 4; t++)                          \
            gload16(Bb + srcoff[t] + ko, &smemB[(bf) * 8192 + ldso[t]]);       \
    }

    f32x4 acc[4][4];
#pragma unroll
    for (int i = 0; i < 4; i++)
#pragma unroll
        for (int j = 0; j < 4; j++) acc[i][j] = (f32x4)0.f;

    constexpr int nK = KK / 64;                   // 4 or 8
    // prologue: A0, B0, A1 issued; wait A0+B0 (A1 stays in flight)
    STAGE_A(0, 0);
    STAGE_B(0, 0);
    STAGE_A(1, 1);
    asm volatile("s_waitcnt vmcnt(4)" ::: "memory");
    __builtin_amdgcn_s_barrier();
    __builtin_amdgcn_sched_barrier(0);

#pragma unroll
    for (int kt = 0; kt < nK; ++kt) {
        if (kt + 1 < nK) STAGE_B(kt + 1, (kt + 1) & 1);
        if (kt + 2 < nK) STAGE_A(kt + 2, (kt + 2) % 3);
        const unsigned short* bufA = &smemA[(kt % 3) * 8192];
        const unsigned short* bufB = &smemB[(kt & 1) * 8192];
#pragma unroll
        for (int h = 0; h < 2; h++) {
            bf16x8 av[4], bv[4];
#pragma unroll
            for (int i = 0; i < 4; i++) av[i] = *(const bf16x8*)&bufA[aoff[i][h]];
#pragma unroll
            for (int j = 0; j < 4; j++) bv[j] = *(const bf16x8*)&bufB[boff[j][h]];
#pragma unroll
            for (int i = 0; i < 4; i++)
#pragma unroll
                for (int j = 0; j < 4; j++)
                    acc[i][j] = __builtin_amdgcn_mfma_f32_16x16x32_bf16(
                        av[i], bv[j], acc[i][j], 0, 0, 0);
        }
        if (kt + 1 < nK) {
            if (kt + 2 < nK) {
                asm volatile("s_waitcnt vmcnt(4)" ::: "memory");  // A(t+2) keeps flying
            } else {
                asm volatile("s_waitcnt vmcnt(0)" ::: "memory");  // tail
            }
            __builtin_amdgcn_s_barrier();
            __builtin_amdgcn_sched_barrier(0);
        }
    }
#undef STAGE_A
#undef STAGE_B

    // epilogue: C/D frag: col = lane&15, row = (lane>>4)*4 + reg   [m89-verified]
    const size_t mw = (size_t)bx * 128 + wm * 64;
    const int n0 = by * 128 + wn * 64;
#pragma unroll
    for (int i = 0; i < 4; i++) {
#pragma unroll
        for (int j = 0; j < 4; j++) {
            const int n = n0 + j * 16 + fr;
            const size_t mbase = mw + i * 16 + c8 * 4;
            if constexpr (EPI == 1 || EPI == 2 || EPI == 3) {
                // rows mbase..mbase+3: dir d == rg (mbase % 4 == 0)
                float bn = bias[n];
                float rv = 0.f;
                if constexpr (EPI == 2) rv = bf2f(resid[(mbase >> 2) * 512 + n]);
                float v[4];
#pragma unroll
                for (int rg = 0; rg < 4; rg++) {
                    float u = acc[i][j][rg] + bn + chan[rg * 512 + n] + rv;
                    v[rg] = (EPI == 3) ? u : leaky(u);
                }
                pack_store_g(out, mbase, n & ~1, fr, v[0], v[1], v[2], v[3]);
            } else {
#pragma unroll
                for (int rg = 0; rg < 4; ++rg) {
                    size_t m = mbase + rg;
                    float v = acc[i][j][rg];
                    if constexpr (EPI == 0) {
                        float v0 = v + bias[n];
#pragma unroll
                        for (int d = 0; d < 4; ++d) {
                            float u = v0 + chan[d * 512 + n];
                            out[(m * 4 + d) * 512 + n] = f2bf(leaky(u));
                        }
                    } else {
                        float u = v + bias[n];
                        out[m * 512 + n] = f2bf(EPI == 4 ? leaky(u) : u);
                    }
                }
            }
        }
    }
}

// ---------------- final: out[64000][2] ----------------
__global__ __launch_bounds__(256) void final_k(
    const unsigned short* __restrict__ A, const float* __restrict__ outW,
    const float* __restrict__ outb, float* __restrict__ out) {
    int gw = blockIdx.x * 4 + (threadIdx.x >> 6);
    int lane = threadIdx.x & 63;
    const unsigned short* row = A + (size_t)gw * 512;
    uint4 bits = *(const uint4*)(row + lane * 8);
    unsigned int ww[4] = {bits.x, bits.y, bits.z, bits.w};
    float s0 = 0.f, s1 = 0.f;
#pragma unroll
    for (int j = 0; j < 8; j++) {
        unsigned short u = (unsigned short)((ww[j >> 1] >> ((j & 1) * 16)) & 0xffff);
        float a = bf2f(u);
        int k = lane * 8 + j;
        s0 = fmaf(a, outW[k * 2 + 0], s0);
        s1 = fmaf(a, outW[k * 2 + 1], s1);
    }
    for (int o = 32; o; o >>= 1) {
        s0 += __shfl_down(s0, o);
        s1 += __shfl_down(s1, o);
    }
    if (lane == 0) {
        out[(size_t)gw * 2 + 0] = s0 + outb[0];
        out[(size_t)gw * 2 + 1] = s1 + outb[1];
    }
}

extern "C" void kernel_launch(void* const* d_in, const int* in_sizes, int n_in,
                              void* d_out, int out_size, void* d_ws, size_t ws_size,
                              hipStream_t stream) {
    const float* input_stuff = (const float*)d_in[0];
    const float* sound_loc   = (const float*)d_in[1];
    const float* grid_xy     = (const float*)d_in[2];
    const float* xy_offset   = (const float*)d_in[3];
    const float* bandwidths  = (const float*)d_in[4];
    const float* grid_0      = (const float*)d_in[5];
    const float* proj_W      = (const float*)d_in[6];
    const float* proj_b      = (const float*)d_in[7];
    const float* res_W0      = (const float*)d_in[8];
    const float* res_b0      = (const float*)d_in[9];
    const float* res_W1      = (const float*)d_in[10];
    const float* res_b1      = (const float*)d_in[11];
    const float* layers_W    = (const float*)d_in[12];
    const float* layers_b    = (const float*)d_in[13];
    const float* channels    = (const float*)d_in[14];
    const float* out_W       = (const float*)d_in[15];
    const float* out_b       = (const float*)d_in[16];

    char* ws = (char*)d_ws;
    float* feats            = (float*)(ws + OFF_FEATS);
    unsigned short* projWT  = (unsigned short*)(ws + OFF_PROJWT);
    unsigned short* res0WT  = (unsigned short*)(ws + OFF_RES0WT);
    unsigned short* res1WT  = (unsigned short*)(ws + OFF_RES1WT);
    unsigned short* layWT   = (unsigned short*)(ws + OFF_LAYWT);
    unsigned short* myin    = (unsigned short*)(ws + OFF_MYIN);
    unsigned short* R0      = (unsigned short*)(ws + OFF_R0);
    unsigned short* Rb      = (unsigned short*)(ws + OFF_R);
    unsigned short* A0      = (unsigned short*)(ws + OFF_A0);
    unsigned short* A1      = (unsigned short*)(ws + OFF_A1);
    float* partial          = (float*)(ws + OFF_A0);

    static int smem_set = 0;
    if (!smem_set) {
        hipFuncSetAttribute((const void*)gemm_k<0, 256>, hipFuncAttributeMaxDynamicSharedMemorySize, 81920);
        hipFuncSetAttribute((const void*)gemm_k<4, 256>, hipFuncAttributeMaxDynamicSharedMemorySize, 81920);
        hipFuncSetAttribute((const void*)gemm_k<5, 512>, hipFuncAttributeMaxDynamicSharedMemorySize, 81920);
        hipFuncSetAttribute((const void*)gemm_k<1, 512>, hipFuncAttributeMaxDynamicSharedMemorySize, 81920);
        hipFuncSetAttribute((const void*)gemm_k<2, 512>, hipFuncAttributeMaxDynamicSharedMemorySize, 81920);
        hipFuncSetAttribute((const void*)gemm_k<3, 512>, hipFuncAttributeMaxDynamicSharedMemorySize, 81920);
        smem_set = 1;
    }

    wconv_k<<<(512 * 256 + 255) / 256, 256, 0, stream>>>(proj_W, projWT, CATCH, CATPAD, IC, 512 * 256);
    wconv_k<<<(512 * 256 + 255) / 256, 256, 0, stream>>>(res_W0, res0WT, CATCH, CATPAD, IC, 512 * 256);
    wconv_k<<<(512 * 512 + 255) / 256, 256, 0, stream>>>(res_W1, res1WT, IC, IC, IC, 512 * 512);
    wconv_k<<<(6 * 512 * 512 + 255) / 256, 256, 0, stream>>>(layers_W, layWT, IC, IC, IC, 6 * 512 * 512);

    feats_part_k<<<dim3(16, NSLICE), 256, 0, stream>>>(grid_xy, xy_offset, bandwidths, grid_0, sound_loc, partial);
    feats_reduce_k<<<16, 128, 0, stream>>>(partial, feats);
    build_k<<<MROWS, 256, 0, stream>>>(feats, input_stuff, myin);

    // proj (+channels[0], leaky, expand x4) -> A0
    gemm_k<0, 256><<<500, 256, 81920, stream>>>(myin, projWT, A0, proj_b, channels, nullptr);
    // residual branch
    gemm_k<4, 256><<<500, 256, 81920, stream>>>(myin, res0WT, R0, res_b0, nullptr, nullptr);
    gemm_k<5, 512><<<500, 256, 81920, stream>>>(R0, res1WT, Rb, res_b1, nullptr, nullptr);
    // 6 layers, ping-pong A0/A1; residual at k==2; k==5 last (no leaky)
    gemm_k<1, 512><<<2000, 256, 81920, stream>>>(A0, layWT + 0 * 262144, A1, layers_b + 0 * 512, channels + 1 * 2048, nullptr);
    gemm_k<1, 512><<<2000, 256, 81920, stream>>>(A1, layWT + 1 * 262144, A0, layers_b + 1 * 512, channels + 2 * 2048, nullptr);
    gemm_k<2, 512><<<2000, 256, 81920, stream>>>(A0, layWT + 2 * 262144, A1, layers_b + 2 * 512, channels + 3 * 2048, Rb);
    gemm_k<1, 512><<<2000, 256, 81920, stream>>>(A1, layWT + 3 * 262144, A0, layers_b + 3 * 512, channels + 4 * 2048, nullptr);
    gemm_k<1, 512><<<2000, 256, 81920, stream>>>(A0, layWT + 4 * 262144, A1, layers_b + 4 * 512, channels + 5 * 2048, nullptr);
    gemm_k<3, 512><<<2000, 256, 81920, stream>>>(A1, layWT + 5 * 262144, A0, layers_b + 5 * 512, channels + 6 * 2048, nullptr);

    final_k<<<MROWS, 256, 0, stream>>>(A0, out_W, out_b, (float*)d_out);
}